// Round 2
// baseline (121.987 us; speedup 1.0000x reference)
//
#include <hip/hip_runtime.h>

#define BB 2
#define NN 1024

// ---------------- K1: a1,c1 from x, W1(6x32), b1 ----------------
// thread per (row i, f) ; rows = B*N = 2048, F = 32
__global__ void k_ac1(const float* __restrict__ x, const float* __restrict__ W1,
                      const float* __restrict__ b1,
                      float* __restrict__ a1, float* __restrict__ c1) {
    int t = blockIdx.x * blockDim.x + threadIdx.x;   // 0 .. 2048*32-1
    int i = t >> 5, f = t & 31;
    float x0 = x[i * 3 + 0], x1 = x[i * 3 + 1], x2 = x[i * 3 + 2];
    float a = x0 * W1[0 * 32 + f] + x1 * W1[1 * 32 + f] + x2 * W1[2 * 32 + f];
    float c = x0 * W1[3 * 32 + f] + x1 * W1[4 * 32 + f] + x2 * W1[5 * 32 + f] + b1[f];
    a1[t] = a;
    c1[t] = c;
}

// ---------------- K2: pair-sum, F=32, relu ----------------
// wave per i; lane = js*32+f (js = j parity split); c staged in LDS 256 rows at a time
__global__ __launch_bounds__(256) void k_pair32(const float* __restrict__ a1,
                                                const float* __restrict__ c1,
                                                float* __restrict__ out1) {
    __shared__ float cbuf[256 * 32];                 // 32 KB
    int wave = threadIdx.x >> 6;                     // 0..3
    int lane = threadIdx.x & 63;
    int js = lane >> 5, f = lane & 31;
    int i = blockIdx.x * 4 + wave;                   // 0..2047
    int b = i >> 10;
    const float* cb = c1 + b * (NN * 32);
    float a = a1[i * 32 + f];
    float acc = 0.f;
    for (int tile = 0; tile < NN; tile += 256) {
        const float4* src = (const float4*)(cb + tile * 32);
        float4* dst = (float4*)cbuf;
        for (int k = threadIdx.x; k < 2048; k += 256) dst[k] = src[k];
        __syncthreads();
        #pragma unroll 8
        for (int jj = js; jj < 256; jj += 2) {
            acc += fmaxf(a + cbuf[jj * 32 + f], 0.f);
        }
        __syncthreads();
    }
    acc += __shfl_xor(acc, 32);
    float self = fmaxf(a + c1[i * 32 + f], 0.f);
    float res = (acc - self) / 1023.0f;
    if (js == 0) out1[i * 32 + f] = res;
}

// ---------------- K3: a2,c2 from out1, W2(64x64), b2 ----------------
// thread per (i, f); F = 64
__global__ void k_ac2(const float* __restrict__ h, const float* __restrict__ W2,
                      const float* __restrict__ b2,
                      float* __restrict__ a2, float* __restrict__ c2) {
    int t = blockIdx.x * blockDim.x + threadIdx.x;   // 0 .. 2048*64-1
    int i = t >> 6, f = t & 63;
    const float* hr = h + i * 32;
    float a = 0.f, c = b2[f];
    #pragma unroll
    for (int d = 0; d < 32; ++d) {
        float hv = hr[d];
        a += hv * W2[d * 64 + f];
        c += hv * W2[(32 + d) * 64 + f];
    }
    a2[t] = a;
    c2[t] = c;
}

// ---------------- K4: pair-sum, F=64, relu ----------------
// wave per i; lane = f; c staged in LDS 128 rows at a time
__global__ __launch_bounds__(256) void k_pair64(const float* __restrict__ a2,
                                                const float* __restrict__ c2,
                                                float* __restrict__ out2) {
    __shared__ float cbuf[128 * 64];                 // 32 KB
    int wave = threadIdx.x >> 6;
    int lane = threadIdx.x & 63;
    int i = blockIdx.x * 4 + wave;                   // 0..2047
    int b = i >> 10;
    const float* cb = c2 + b * (NN * 64);
    float a = a2[i * 64 + lane];
    float acc = 0.f;
    for (int tile = 0; tile < NN; tile += 128) {
        const float4* src = (const float4*)(cb + tile * 64);
        float4* dst = (float4*)cbuf;
        for (int k = threadIdx.x; k < 2048; k += 256) dst[k] = src[k];
        __syncthreads();
        #pragma unroll 8
        for (int jj = 0; jj < 128; ++jj) {
            acc += fmaxf(a + cbuf[jj * 64 + lane], 0.f);
        }
        __syncthreads();
    }
    float self = fmaxf(a + c2[i * 64 + lane], 0.f);
    out2[i * 64 + lane] = (acc - self) / 1023.0f;
}

// ---------------- K5a: colsum(out2) @ W3bot -> S[b][3] ----------------
__global__ void k_colsum(const float* __restrict__ out2, const float* __restrict__ W3,
                         float* __restrict__ S) {
    __shared__ float part[4][64];
    __shared__ float colsum[64];
    int b = blockIdx.x;
    int t = threadIdx.x;
    int d = t & 63, chunk = t >> 6;
    const float* base = out2 + b * (NN * 64);
    float s = 0.f;
    for (int j = chunk * 256; j < chunk * 256 + 256; ++j) s += base[j * 64 + d];
    part[chunk][d] = s;
    __syncthreads();
    if (t < 64) colsum[t] = part[0][t] + part[1][t] + part[2][t] + part[3][t];
    __syncthreads();
    if (t < 3) {
        float acc = 0.f;
        for (int d2 = 0; d2 < 64; ++d2) acc += colsum[d2] * W3[(64 + d2) * 3 + t];
        S[b * 3 + t] = acc;
    }
}

// ---------------- K5b: separable final layer (no relu) ----------------
// thread per (b,i)
__global__ void k_final(const float* __restrict__ out2, const float* __restrict__ W3,
                        const float* __restrict__ b3, const float* __restrict__ S,
                        float* __restrict__ out) {
    int t = blockIdx.x * blockDim.x + threadIdx.x;   // 0..2047
    int b = t >> 10;
    const float* row = out2 + t * 64;
    float a0 = 0, a1 = 0, a2 = 0, c0 = 0, c1 = 0, c2 = 0;
    #pragma unroll
    for (int d = 0; d < 64; ++d) {
        float v = row[d];
        a0 += v * W3[d * 3 + 0];
        a1 += v * W3[d * 3 + 1];
        a2 += v * W3[d * 3 + 2];
        c0 += v * W3[(64 + d) * 3 + 0];
        c1 += v * W3[(64 + d) * 3 + 1];
        c2 += v * W3[(64 + d) * 3 + 2];
    }
    float* o = out + t * 3;
    o[0] = a0 + b3[0] + (S[b * 3 + 0] - c0) / 1023.0f;
    o[1] = a1 + b3[1] + (S[b * 3 + 1] - c1) / 1023.0f;
    o[2] = a2 + b3[2] + (S[b * 3 + 2] - c2) / 1023.0f;
}

extern "C" void kernel_launch(void* const* d_in, const int* in_sizes, int n_in,
                              void* d_out, int out_size, void* d_ws, size_t ws_size,
                              hipStream_t stream) {
    const float* x  = (const float*)d_in[0];   // (2, 3072)
    const float* W1 = (const float*)d_in[1];   // (6, 32)
    const float* b1 = (const float*)d_in[2];   // (32,)
    const float* W2 = (const float*)d_in[3];   // (64, 64)
    const float* b2 = (const float*)d_in[4];   // (64,)
    const float* W3 = (const float*)d_in[5];   // (128, 3)
    const float* b3 = (const float*)d_in[6];   // (3,)
    float* out = (float*)d_out;                // (2, 3072)

    float* ws = (float*)d_ws;
    float* a1   = ws;                          // 2048*32
    float* c1   = a1 + 2048 * 32;              // 2048*32
    float* out1 = c1 + 2048 * 32;              // 2048*32
    float* a2   = out1 + 2048 * 32;            // 2048*64
    float* c2   = a2 + 2048 * 64;              // 2048*64
    float* out2 = c2 + 2048 * 64;              // 2048*64
    float* S    = out2 + 2048 * 64;            // 6

    k_ac1<<<(2048 * 32) / 256, 256, 0, stream>>>(x, W1, b1, a1, c1);
    k_pair32<<<512, 256, 0, stream>>>(a1, c1, out1);
    k_ac2<<<(2048 * 64) / 256, 256, 0, stream>>>(out1, W2, b2, a2, c2);
    k_pair64<<<512, 256, 0, stream>>>(a2, c2, out2);
    k_colsum<<<2, 256, 0, stream>>>(out2, W3, S);
    k_final<<<2048 / 256, 256, 0, stream>>>(out2, W3, b3, S, out);
}